// Round 11
// baseline (2979.007 us; speedup 1.0000x reference)
//
#include <hip/hip_runtime.h>
#include <hip/hip_bf16.h>

#define SEQT 2000
#define NB   2048
#define H1   51
#define MROW 16            // rows per problem
#define NPRB 2             // independent problems per block (share barriers)
#define NBLK (NB / (MROW * NPRB))   // 64 blocks, 256 threads (4 waves)
#define PADK 168           // shorts per staged row (336 B = 21*16, 16B-aligned)
#define OSTR 65            // Obuf row stride (floats) — odd, conflict-free

// log2(e) and 2*log2(e)
#define L2E  1.4426950408889634f
#define L2E2 2.8853900817779268f

typedef float f32x4 __attribute__((ext_vector_type(4)));
typedef short s16x8 __attribute__((ext_vector_type(8)));
typedef unsigned u32x4 __attribute__((ext_vector_type(4)));
typedef unsigned u32x2 __attribute__((ext_vector_type(2)));

#if __has_builtin(__builtin_amdgcn_exp2f)
#define EXP2F(x) __builtin_amdgcn_exp2f(x)
#else
#define EXP2F(x) __expf((x) * 0.6931471805599453f)   // exp(x*ln2) == 2^x
#endif

__device__ __forceinline__ short f2bf(float f) { __hip_bfloat16 b(f); return *(short*)&b; }
__device__ __forceinline__ float bf2f(short s) { __hip_bfloat16 b; *(short*)&b = s; return (float)b; }
__device__ __forceinline__ float rbf(float f) { return bf2f(f2bf(f)); }
__device__ __forceinline__ float fastrcp(float x) { return __builtin_amdgcn_rcpf(x); }
__device__ __forceinline__ float tanhfast(float x) {
    return 1.f - 2.f * fastrcp(EXP2F(x * L2E2) + 1.f);
}

__device__ __forceinline__ unsigned rne_bf16(float v) {
    unsigned b = __float_as_uint(v);
    return (b + 0x7fffu + ((b >> 16) & 1u)) >> 16;
}
// packed (hi | lo<<16), both RNE — off the hot path (x staging)
__device__ __forceinline__ unsigned pack_hilo(float v) {
    const unsigned hh = rne_bf16(v);
    const float hi = __uint_as_float(hh << 16);
    const unsigned hl = rne_bf16(v - hi);
    return hh | (hl << 16);
}

__device__ __forceinline__ f32x4 mfma16(s16x8 a, s16x8 b, f32x4 c) {
    return __builtin_amdgcn_mfma_f32_16x16x32_bf16(a, b, c, 0, 0, 0);
}

// ---------------------------------------------------------------------------
// TWO-PROBLEM FUSION: each block runs TWO independent 16-row LSTM recurrences
// (rows r0..r0+15 and r0+16..r0+31) through the SAME barrier cadence. Weights
// (Wfr, Wz) are shared; per-problem state/LDS duplicated with static indices.
// Rationale: per-step time = busiest-wave issue + fixed barrier/latency cost C
// (r6/r9: removing issue no longer helps; r7: adding tail hurts 1:1). Fusing
// two steps per interval amortizes C over 2 logical steps.
//
// Staged-vector column map, K=160 (5 k-tiles of 32), per problem:
//   0..95   : (h_hi,h_lo) pairs vs Whh_hi. col=(sl*4+kq)*8+2i+{0,1}, tile=sl*4+i
//   96..101 : w1 pairs (u=48+kq, kq=0..2) vs Whh_hi
//   102,103 : x_hi, x_lo vs Wih_hi
//   104..151: h_hi singles vs Whh_lo. col=104+(sl*4+kq)*4+i
//   152..154: w1 singles (u=48+kq) vs Whh_lo
//   155     : x_hi vs Wih_lo
//   156,157 : 1.0 vs bias_hi / bias_lo    158,159: 0    160..167: scratch
// EXP2 FOLD: A-rows pre-scaled by -log2e (i/f/o) or -2log2e (g) so
// e_gate = exp2(acc) directly off the MFMA accumulator.
// MFMA: single-accumulator chains (r7/r8 A/B: dual-acc join costs ~150 cy).
// LSTM3 (H3=1) on w1 for BOTH problems: 52-FMA dot (8 acc), 64-lane activation
// spread, shfl_xor gate gather, c3/h3 on lanes 0..15.
// Roles: w0 SL0, w2 SL1 + x-staging(A,B), w3 SL2 + Xbuf fill(B),
//        w1 tile12(A,B) + LSTM3(A,B) + Xbuf fill(A).
// ---------------------------------------------------------------------------

__device__ __forceinline__ float aval(const float* __restrict__ W_hh1,
                                      const float* __restrict__ W_ih1,
                                      const float* __restrict__ b_ih1,
                                      const float* __restrict__ b_hh1,
                                      int n, float sc, bool vr, int k) {
    if (!vr) return 0.f;
    if (k < 96) {
        const int gp = k >> 3, j = k & 7;
        const int u = 4 * ((gp >> 2) * 4 + (j >> 1)) + (gp & 3);
        return rbf(sc * W_hh1[n * H1 + u]);
    } else if (k < 102) {
        const int u = 48 + ((k - 96) >> 1);
        return rbf(sc * W_hh1[n * H1 + u]);
    } else if (k < 104) {
        return rbf(sc * W_ih1[n]);               // x_hi / x_lo vs Wih_hi
    } else if (k < 152) {
        const int d = k - 104;
        const int gp = d >> 2;
        const int u = 4 * ((gp >> 2) * 4 + (d & 3)) + (gp & 3);
        const float wv = sc * W_hh1[n * H1 + u];
        return wv - rbf(wv);
    } else if (k < 155) {
        const int u = 48 + (k - 152);
        const float wv = sc * W_hh1[n * H1 + u];
        return wv - rbf(wv);
    } else if (k == 155) {
        const float wv = sc * W_ih1[n];
        return wv - rbf(wv);
    } else if (k == 156) {
        return rbf(sc * (b_ih1[n] + b_hh1[n]));
    } else if (k == 157) {
        const float bv = sc * (b_ih1[n] + b_hh1[n]);
        return bv - rbf(bv);
    }
    return 0.f;
}

template <int SL, int NTc>
__device__ __forceinline__ void run_tiles(const s16x8 (&Wfr)[4][5], const s16x8 (&hf)[5],
                                          float (&c1st)[4], short* __restrict__ Hw,
                                          float* __restrict__ C1w,
                                          const int iloc, const int kq) {
    f32x4 acc[4];
#pragma unroll
    for (int i = 0; i < NTc; ++i) {
        // single accumulator chain (independent tiles pipeline the latency)
        f32x4 a = (f32x4){0.f, 0.f, 0.f, 0.f};
        a = mfma16(Wfr[i][0], hf[0], a);
        a = mfma16(Wfr[i][1], hf[1], a);
        a = mfma16(Wfr[i][2], hf[2], a);
        a = mfma16(Wfr[i][3], hf[3], a);
        a = mfma16(Wfr[i][4], hf[4], a);
        acc[i] = a;
    }
    unsigned hp[4];
    float cl[4];
#pragma unroll
    for (int i = 0; i < NTc; ++i) {
        // acc already holds the exp2 arguments (weights pre-scaled).
        const float ei = EXP2F(acc[i][0]);        // e^{-gi}
        const float ef = EXP2F(acc[i][1]);        // e^{-gf}
        const float eg = EXP2F(acc[i][2]);        // e^{-2gg}
        const float eo = EXP2F(acc[i][3]);        // e^{-go}
        const float pf = 1.f + ef, pi_ = 1.f + ei, pg = 1.f + eg, mg = 1.f - eg;
        const float pp = pi_ * pg;
        float c1 = c1st[i];
        c1 = fmaf(c1, pp, pf * mg) * fastrcp(pf * pp);
        c1st[i] = c1;
        cl[i] = c1;
        // h1 = sig(go)*tanh(c1); clamp matches exp-domain 80 (115.4/log2e)
        const float ec = EXP2F(fminf(115.4f, c1 * -L2E2));
        const float h1 = (1.f - ec) * fastrcp((1.f + eo) * (1.f + ec));
        // RNE hi + RNE lo via HW bf16 converts
        const __hip_bfloat16 bh(h1);
        const float df = h1 - (float)bh;
        const __hip_bfloat16 bl(df);
        hp[i] = (unsigned)*(const unsigned short*)&bh |
                ((unsigned)*(const unsigned short*)&bl << 16);
    }
    const int base = iloc * PADK;
    if (NTc == 4) {
        *(u32x4*)&Hw[base + (SL * 4 + kq) * 8] =
            (u32x4){hp[0], hp[1], hp[2], hp[3]};
        const unsigned s01 = (hp[0] & 0xffffu) | (hp[1] << 16);
        const unsigned s23 = (hp[2] & 0xffffu) | (hp[3] << 16);
        *(u32x2*)&Hw[base + 104 + (SL * 4 + kq) * 4] = (u32x2){s01, s23};
        *(f32x4*)&C1w[iloc * 52 + SL * 16 + kq * 4] =
            (f32x4){cl[0], cl[1], cl[2], cl[3]};
    } else {
        const bool ok = (48 + kq) < H1;           // kq==3 -> scratch
        *(unsigned*)&Hw[base + (ok ? 96 + 2 * kq : 160)] = hp[0];
        Hw[base + (ok ? 152 + kq : 164)] = (short)hp[0];
        C1w[iloc * 52 + 48 + kq] = cl[0];         // p=51 is scratch (Wz[51]=0)
    }
}

// Fill one 32-step x-chunk into a problem's Xbuf (one wave, all 64 lanes).
__device__ __forceinline__ void xfill32(const float* __restrict__ input, int rbase, int c,
                                        int lane, unsigned (*Xb)[32 * 16]) {
    const int m = lane & 15, q = lane >> 4;
    const int tt = c * 32 + q * 8;
    f32x4 v0, v1;
    if (tt < SEQT) {
        const float* src = input + (size_t)(rbase + m) * SEQT + tt;
        v0 = *(const f32x4*)src;
        v1 = *(const f32x4*)(src + 4);
    } else {
        v0 = (f32x4){0.f, 0.f, 0.f, 0.f};
        v1 = v0;
    }
#pragma unroll
    for (int j = 0; j < 4; ++j)
        Xb[c & 1][(q * 8 + j) * 16 + m] = pack_hilo(v0[j]);
#pragma unroll
    for (int j = 0; j < 4; ++j)
        Xb[c & 1][(q * 8 + 4 + j) * 16 + m] = pack_hilo(v1[j]);
}

__global__ void __launch_bounds__(256)
__attribute__((amdgpu_waves_per_eu(1)))
lstm_fused_kernel(const float* __restrict__ input,
                  const float* __restrict__ W_ih1,
                  const float* __restrict__ W_hh1,
                  const float* __restrict__ b_ih1,
                  const float* __restrict__ b_hh1,
                  const float* __restrict__ W_ih3,
                  const float* __restrict__ W_hh3,
                  const float* __restrict__ b_ih3,
                  const float* __restrict__ b_hh3,
                  float* __restrict__ out) {
    const int t = threadIdx.x;
    const int w = t >> 6;          // wave 0..3
    const int lane = t & 63;
    const int iloc = lane & 15, kq = lane >> 4;
    const int r0 = blockIdx.x * (MROW * NPRB);

    __shared__ short Hst[NPRB][2][MROW * PADK];      // staged rows, parity dbuf
    __shared__ float C1buf[NPRB][2][MROW * 52];      // raw f32 c1, parity dbuf
    __shared__ float Obuf[NPRB][2][MROW * OSTR];     // c3 chunks (64-step)
    __shared__ unsigned Xbuf[NPRB][2][32 * 16];      // packed x, 32-step chunks

    // tile assignment per problem: w0 SL0{0-3}, w2 SL1{4-7}, w3 SL2{8-11},
    // w1 SL3{12}+LSTM3
    const int NT = (w == 1) ? 1 : 4;
    const int tb = (w == 0) ? 0 : (w == 1) ? 12 : (w == 2) ? 4 : 8;

    // ---- gate-row weight fragments (shared by both problems) ----
    s16x8 Wfr[4][5];
#pragma unroll
    for (int i = 0; i < 4; ++i) {
        if (i < NT) {
            const int np = (tb + i) * 16 + iloc;
            const int u_r = np >> 2, g_r = np & 3;
            const int n = g_r * H1 + u_r;
            const bool vr = (u_r < H1);
            const float sc = (g_r == 2) ? -L2E2 : -L2E;
#pragma unroll
            for (int kt = 0; kt < 5; ++kt) {
                s16x8 bf;
#pragma unroll
                for (int j = 0; j < 8; ++j)
                    bf[j] = f2bf(aval(W_hh1, W_ih1, b_ih1, b_hh1, n, sc, vr,
                                      kt * 32 + kq * 8 + j));
                Wfr[i][kt] = bf;
            }
        }
    }

    // ---- wave 1: LSTM3 constants (log2-scaled, shared). lane (m,g3) ----
    const int g3 = lane >> 4;
    const float scg3 = (g3 == 2) ? L2E2 : -L2E;   // kg * log2e
    float Wz[52];
    if (w == 1) {
#pragma unroll
        for (int p = 0; p < 52; ++p) {
            const int u = (p < 48) ? (16 * (p >> 4) + 4 * (p & 3) + ((p >> 2) & 3))
                                   : p;
            Wz[p] = (u < H1) ? scg3 * W_ih3[g3 * H1 + u] : 0.f;
        }
    }
    const float whh3g = scg3 * W_hh3[g3];
    const float b3g = scg3 * (b_ih3[g3] + b_hh3[g3]);
    const float ag = (g3 == 2) ? -2.f : 1.f;
    const float bg = (g3 == 2) ? 1.f : 0.f;

    // ---- LDS init ----
    for (int idx = t; idx < NPRB * 2 * MROW * PADK; idx += 256)
        ((short*)Hst)[idx] = 0;
    for (int idx = t; idx < NPRB * 2 * MROW * 52; idx += 256)
        ((float*)C1buf)[idx] = 0.f;
    __syncthreads();   // zeros before targeted writes
    if (t < MROW * NPRB) {     // 32 threads: (problem, row)
        const int p = t >> 4, m = t & 15;
#pragma unroll
        for (int par = 0; par < 2; ++par) {
            Hst[p][par][m * PADK + 156] = (short)0x3F80;   // 1.0 (bias cols)
            Hst[p][par][m * PADK + 157] = (short)0x3F80;
        }
        const float x0 = input[(size_t)(r0 + p * 16 + m) * SEQT];
        const unsigned xp = pack_hilo(x0);
        Hst[p][1][m * PADK + 102] = (short)xp;   // window 0 reads parity 1
        Hst[p][1][m * PADK + 103] = (short)(xp >> 16);
        Hst[p][1][m * PADK + 155] = (short)xp;
    }
    if (w == 1) {              // prefill x chunks 0,1 — problem A
        xfill32(input, r0, 0, lane, Xbuf[0]);
        xfill32(input, r0, 1, lane, Xbuf[0]);
    }
    if (w == 3) {              // prefill x chunks 0,1 — problem B
        xfill32(input, r0 + 16, 0, lane, Xbuf[1]);
        xfill32(input, r0 + 16, 1, lane, Xbuf[1]);
    }
    float c1stA[4] = {0.f, 0.f, 0.f, 0.f};
    float c1stB[4] = {0.f, 0.f, 0.f, 0.f};
    float h3A = 0.f, c3A = 0.f, h3bA = 0.f;   // LSTM3 state per problem
    float h3B = 0.f, c3B = 0.f, h3bB = 0.f;

#pragma unroll 1
    for (int ts = 0; ts <= SEQT; ++ts) {
        __syncthreads();
        const int rb = (ts + 1) & 1, wb = ts & 1;

        // ---- reads first: LDS latency overlaps the interval ----
        s16x8 hfA[5], hfB[5];
        if (ts < SEQT) {
#pragma unroll
            for (int kt = 0; kt < 5; ++kt)
                hfA[kt] = *(const s16x8*)&Hst[0][rb][iloc * PADK + kt * 32 + kq * 8];
#pragma unroll
            for (int kt = 0; kt < 5; ++kt)
                hfB[kt] = *(const s16x8*)&Hst[1][rb][iloc * PADK + kt * 32 + kq * 8];
        }
        f32x4 c1vA[13];
        if (w == 1 && ts >= 1) {
            const float* cr = &C1buf[0][rb][(lane & 15) * 52];
#pragma unroll
            for (int j = 0; j < 13; ++j)
                c1vA[j] = *(const f32x4*)(cr + 4 * j);
        }

        // ---- coalesced dump of finished 64-chunk (both problems) ----
        if (ts >= 65 && (ts & 63) == 1) {
            const int c = (ts >> 6) - 1;
#pragma unroll
            for (int p = 0; p < NPRB; ++p)
#pragma unroll
                for (int rep = 0; rep < 4; ++rep) {
                    const int row = w + 4 * rep;
                    out[(size_t)(r0 + p * 16 + row) * SEQT + c * 64 + lane] =
                        Obuf[p][c & 1][row * OSTR + lane];
                }
        }

        // ---- x chunk prefetch: w1 loads A, w3 loads B (store at bottom) ----
        const bool fill = (ts < SEQT) && ((ts & 31) == 0) && (ts >= 32) &&
                          ((ts >> 5) < 62) && (w == 1 || w == 3);
        const int fc = (ts >> 5) + 1;
        f32x4 xv0, xv1;
        if (fill) {
            const int rbase = r0 + ((w == 3) ? 16 : 0);
            const int fm = lane & 15, fq = lane >> 4;
            const int tt = fc * 32 + fq * 8;
            if (tt < SEQT) {
                const float* src = input + (size_t)(rbase + fm) * SEQT + tt;
                xv0 = *(const f32x4*)src;
                xv1 = *(const f32x4*)(src + 4);
            } else {
                xv0 = (f32x4){0.f, 0.f, 0.f, 0.f};
                xv1 = xv0;
            }
        }

        if (ts < SEQT) {
            short* HwA = &Hst[0][wb][0];
            short* HwB = &Hst[1][wb][0];
            float* C1wA = &C1buf[0][wb][0];
            float* C1wB = &C1buf[1][wb][0];
            if (w == 0) {
                run_tiles<0, 4>(Wfr, hfA, c1stA, HwA, C1wA, iloc, kq);
                run_tiles<0, 4>(Wfr, hfB, c1stB, HwB, C1wB, iloc, kq);
            } else if (w == 2) {
                // x staging for step ts+1, both problems (cols 102/103/155)
                const int t1 = ts + 1;
                if (t1 < SEQT) {
                    const int m2 = lane & 15;
                    const unsigned pvA = Xbuf[0][(t1 >> 5) & 1][(t1 & 31) * 16 + m2];
                    *(unsigned*)&HwA[m2 * PADK + 102] = pvA;
                    HwA[m2 * PADK + 155] = (short)pvA;
                    const unsigned pvB = Xbuf[1][(t1 >> 5) & 1][(t1 & 31) * 16 + m2];
                    *(unsigned*)&HwB[m2 * PADK + 102] = pvB;
                    HwB[m2 * PADK + 155] = (short)pvB;
                }
                run_tiles<1, 4>(Wfr, hfA, c1stA, HwA, C1wA, iloc, kq);
                run_tiles<1, 4>(Wfr, hfB, c1stB, HwB, C1wB, iloc, kq);
            } else if (w == 3) {
                run_tiles<2, 4>(Wfr, hfA, c1stA, HwA, C1wA, iloc, kq);
                run_tiles<2, 4>(Wfr, hfB, c1stB, HwB, C1wB, iloc, kq);
            } else {
                run_tiles<3, 1>(Wfr, hfA, c1stA, HwA, C1wA, iloc, kq);
                run_tiles<3, 1>(Wfr, hfB, c1stB, HwB, C1wB, iloc, kq);
            }
        }

        // ---- LSTM3 for step ts-1, both problems (wave 1) ----
        if (w == 1 && ts >= 1) {
            // issue B's c1 reads now; latency hides under LSTM3-A's chain
            f32x4 c1vB[13];
            {
                const float* cr = &C1buf[1][rb][(lane & 15) * 52];
#pragma unroll
                for (int j = 0; j < 13; ++j)
                    c1vB[j] = *(const f32x4*)(cr + 4 * j);
            }
            const int s = ts - 1;
            // --- problem A ---
            {
                float d0a = 0.f, d1a = 0.f, d2a = 0.f, d3a = 0.f;
                float d0b = 0.f, d1b = 0.f, d2b = 0.f, d3b = 0.f;
#pragma unroll
                for (int j = 0; j < 13; ++j) {
                    if ((j & 1) == 0) {
                        d0a = fmaf(Wz[4 * j + 0], c1vA[j][0], d0a);
                        d1a = fmaf(Wz[4 * j + 1], c1vA[j][1], d1a);
                        d2a = fmaf(Wz[4 * j + 2], c1vA[j][2], d2a);
                        d3a = fmaf(Wz[4 * j + 3], c1vA[j][3], d3a);
                    } else {
                        d0b = fmaf(Wz[4 * j + 0], c1vA[j][0], d0b);
                        d1b = fmaf(Wz[4 * j + 1], c1vA[j][1], d1b);
                        d2b = fmaf(Wz[4 * j + 2], c1vA[j][2], d2b);
                        d3b = fmaf(Wz[4 * j + 3], c1vA[j][3], d3b);
                    }
                }
                const float z = ((d0a + d0b) + (d1a + d1b)) +
                                ((d2a + d2b) + (d3a + d3b));
                const float pre = z + fmaf(whh3g, h3bA, b3g);
                const float act = bg + ag * fastrcp(EXP2F(pre) + 1.f);
                const float act1 = __shfl_xor(act, 16, 64);
                const float act2 = __shfl_xor(act, 32, 64);
                const float act3 = __shfl_xor(act, 48, 64);
                if (lane < MROW) {
                    c3A = act1 * c3A + act * act2;
                    h3A = act3 * tanhfast(c3A);
                    Obuf[0][(s >> 6) & 1][lane * OSTR + (s & 63)] = c3A;
                }
                h3bA = __shfl(h3A, lane & 15, 64);
            }
            // --- problem B ---
            {
                float d0a = 0.f, d1a = 0.f, d2a = 0.f, d3a = 0.f;
                float d0b = 0.f, d1b = 0.f, d2b = 0.f, d3b = 0.f;
#pragma unroll
                for (int j = 0; j < 13; ++j) {
                    if ((j & 1) == 0) {
                        d0a = fmaf(Wz[4 * j + 0], c1vB[j][0], d0a);
                        d1a = fmaf(Wz[4 * j + 1], c1vB[j][1], d1a);
                        d2a = fmaf(Wz[4 * j + 2], c1vB[j][2], d2a);
                        d3a = fmaf(Wz[4 * j + 3], c1vB[j][3], d3a);
                    } else {
                        d0b = fmaf(Wz[4 * j + 0], c1vB[j][0], d0b);
                        d1b = fmaf(Wz[4 * j + 1], c1vB[j][1], d1b);
                        d2b = fmaf(Wz[4 * j + 2], c1vB[j][2], d2b);
                        d3b = fmaf(Wz[4 * j + 3], c1vB[j][3], d3b);
                    }
                }
                const float z = ((d0a + d0b) + (d1a + d1b)) +
                                ((d2a + d2b) + (d3a + d3b));
                const float pre = z + fmaf(whh3g, h3bB, b3g);
                const float act = bg + ag * fastrcp(EXP2F(pre) + 1.f);
                const float act1 = __shfl_xor(act, 16, 64);
                const float act2 = __shfl_xor(act, 32, 64);
                const float act3 = __shfl_xor(act, 48, 64);
                if (lane < MROW) {
                    c3B = act1 * c3B + act * act2;
                    h3B = act3 * tanhfast(c3B);
                    Obuf[1][(s >> 6) & 1][lane * OSTR + (s & 63)] = c3B;
                }
                h3bB = __shfl(h3B, lane & 15, 64);
            }
        }

        // ---- x chunk prefetch: pack + store (loads had the interval to land) ----
        if (fill) {
            const int p = (w == 3) ? 1 : 0;
            const int fm = lane & 15, fq = lane >> 4;
#pragma unroll
            for (int j = 0; j < 4; ++j)
                Xbuf[p][fc & 1][(fq * 8 + j) * 16 + fm] = pack_hilo(xv0[j]);
#pragma unroll
            for (int j = 0; j < 4; ++j)
                Xbuf[p][fc & 1][(fq * 8 + 4 + j) * 16 + fm] = pack_hilo(xv1[j]);
        }
    }

    __syncthreads();
    // tail: steps 1984..1999 (chunk 31, parity 1), both problems
#pragma unroll
    for (int p = 0; p < NPRB; ++p) {
        const int row = t >> 4, pos = t & 15;
        out[(size_t)(r0 + p * 16 + row) * SEQT + 1984 + pos] =
            Obuf[p][1][row * OSTR + pos];
    }
}

extern "C" void kernel_launch(void* const* d_in, const int* in_sizes, int n_in,
                              void* d_out, int out_size, void* d_ws, size_t ws_size,
                              hipStream_t stream) {
    const float* input = (const float*)d_in[0];
    const float* W_ih1 = (const float*)d_in[1];
    const float* W_hh1 = (const float*)d_in[2];
    const float* b_ih1 = (const float*)d_in[3];
    const float* b_hh1 = (const float*)d_in[4];
    const float* W_ih3 = (const float*)d_in[5];
    const float* W_hh3 = (const float*)d_in[6];
    const float* b_ih3 = (const float*)d_in[7];
    const float* b_hh3 = (const float*)d_in[8];
    float* out = (float*)d_out;

    lstm_fused_kernel<<<NBLK, 256, 0, stream>>>(
        input, W_ih1, W_hh1, b_ih1, b_hh1, W_ih3, W_hh3, b_ih3, b_hh3, out);
}

// Round 12
// 1463.366 us; speedup vs baseline: 2.0357x; 2.0357x over previous
//
#include <hip/hip_runtime.h>
#include <hip/hip_bf16.h>

#define SEQT 2000
#define NB   2048
#define H1   51
#define MROW 16
#define NBLK (NB / MROW)   // 128 blocks, 256 threads (4 waves)
#define PADK 168           // shorts per staged row (336 B = 21*16, 16B-aligned)
#define OSTR 65            // Obuf row stride (floats) — odd, conflict-free

// log2(e) and 2*log2(e)
#define L2E  1.4426950408889634f
#define L2E2 2.8853900817779268f

typedef float f32x4 __attribute__((ext_vector_type(4)));
typedef short s16x8 __attribute__((ext_vector_type(8)));
typedef unsigned u32x4 __attribute__((ext_vector_type(4)));
typedef unsigned u32x2 __attribute__((ext_vector_type(2)));

#if __has_builtin(__builtin_amdgcn_exp2f)
#define EXP2F(x) __builtin_amdgcn_exp2f(x)
#else
#define EXP2F(x) __expf((x) * 0.6931471805599453f)   // exp(x*ln2) == 2^x
#endif

__device__ __forceinline__ short f2bf(float f) { __hip_bfloat16 b(f); return *(short*)&b; }
__device__ __forceinline__ float bf2f(short s) { __hip_bfloat16 b; *(short*)&b = s; return (float)b; }
__device__ __forceinline__ float rbf(float f) { return bf2f(f2bf(f)); }
__device__ __forceinline__ float fastrcp(float x) { return __builtin_amdgcn_rcpf(x); }
__device__ __forceinline__ float tanhfast(float x) {
    return 1.f - 2.f * fastrcp(EXP2F(x * L2E2) + 1.f);
}

__device__ __forceinline__ unsigned rne_bf16(float v) {
    unsigned b = __float_as_uint(v);
    return (b + 0x7fffu + ((b >> 16) & 1u)) >> 16;
}
// packed (hi | lo<<16), both RNE — off the hot path (x staging)
__device__ __forceinline__ unsigned pack_hilo(float v) {
    const unsigned hh = rne_bf16(v);
    const float hi = __uint_as_float(hh << 16);
    const unsigned hl = rne_bf16(v - hi);
    return hh | (hl << 16);
}

__device__ __forceinline__ f32x4 mfma16(s16x8 a, s16x8 b, f32x4 c) {
    return __builtin_amdgcn_mfma_f32_16x16x32_bf16(a, b, c, 0, 0, 0);
}

// ---------------------------------------------------------------------------
// Staged-vector column map, K=160 (5 k-tiles of 32). Columns permuted so every
// per-step write is coalesced; x and bias live inside the matmul.
//   0..95   : (h_hi,h_lo) pairs vs Whh_hi. col=(sl*4+kq)*8+2i+{0,1}, tile=sl*4+i
//   96..101 : w1 pairs (u=48+kq, kq=0..2) vs Whh_hi
//   102,103 : x_hi, x_lo vs Wih_hi
//   104..151: h_hi singles vs Whh_lo. col=104+(sl*4+kq)*4+i
//   152..154: w1 singles (u=48+kq) vs Whh_lo
//   155     : x_hi vs Wih_lo
//   156,157 : 1.0 vs bias_hi / bias_lo    158,159: 0    160..167: scratch
// EXP2 FOLD: A-rows pre-scaled by -log2e (i/f/o) / -2log2e (g) so
// e_gate = exp2(acc) directly off the MFMA accumulator.
// MFMA: single-accumulator chains (r7/r8 A/B: dual-acc join costs ~150 cy).
// LSTM3 (H3=1): w1 reads C1 rows, 52-FMA dot (8 acc), 64-lane activation
// spread, shfl_xor gate gather, c3/h3 on lanes 0..15.
// HOT-LOOP SPECIALIZATION (r11): step loop unrolled x2 with COMPILE-TIME
// parity (all LDS buffer indices constant); even steps carry only the x-chunk
// fill (trigger ts%64==0 is even-only), odd steps carry only the output dump
// (ts%64==1 is odd-only); no ts<SEQT guards (exact bounds, epilogue hoisted).
// Numerics identical to the 1905-us r9 kernel.
// ---------------------------------------------------------------------------

__device__ __forceinline__ float aval(const float* __restrict__ W_hh1,
                                      const float* __restrict__ W_ih1,
                                      const float* __restrict__ b_ih1,
                                      const float* __restrict__ b_hh1,
                                      int n, float sc, bool vr, int k) {
    if (!vr) return 0.f;
    if (k < 96) {
        const int gp = k >> 3, j = k & 7;
        const int u = 4 * ((gp >> 2) * 4 + (j >> 1)) + (gp & 3);
        return rbf(sc * W_hh1[n * H1 + u]);
    } else if (k < 102) {
        const int u = 48 + ((k - 96) >> 1);
        return rbf(sc * W_hh1[n * H1 + u]);
    } else if (k < 104) {
        return rbf(sc * W_ih1[n]);               // x_hi / x_lo vs Wih_hi
    } else if (k < 152) {
        const int d = k - 104;
        const int gp = d >> 2;
        const int u = 4 * ((gp >> 2) * 4 + (d & 3)) + (gp & 3);
        const float wv = sc * W_hh1[n * H1 + u];
        return wv - rbf(wv);
    } else if (k < 155) {
        const int u = 48 + (k - 152);
        const float wv = sc * W_hh1[n * H1 + u];
        return wv - rbf(wv);
    } else if (k == 155) {
        const float wv = sc * W_ih1[n];
        return wv - rbf(wv);
    } else if (k == 156) {
        return rbf(sc * (b_ih1[n] + b_hh1[n]));
    } else if (k == 157) {
        const float bv = sc * (b_ih1[n] + b_hh1[n]);
        return bv - rbf(bv);
    }
    return 0.f;
}

template <int SL, int NTc>
__device__ __forceinline__ void run_tiles(const s16x8 (&Wfr)[4][5], const s16x8 (&hf)[5],
                                          float (&c1st)[4], short* __restrict__ Hw,
                                          float* __restrict__ C1w,
                                          const int iloc, const int kq) {
    f32x4 acc[4];
#pragma unroll
    for (int i = 0; i < NTc; ++i) {
        // single accumulator chain (independent tiles pipeline the latency)
        f32x4 a = (f32x4){0.f, 0.f, 0.f, 0.f};
        a = mfma16(Wfr[i][0], hf[0], a);
        a = mfma16(Wfr[i][1], hf[1], a);
        a = mfma16(Wfr[i][2], hf[2], a);
        a = mfma16(Wfr[i][3], hf[3], a);
        a = mfma16(Wfr[i][4], hf[4], a);
        acc[i] = a;
    }
    unsigned hp[4];
    float cl[4];
#pragma unroll
    for (int i = 0; i < NTc; ++i) {
        // acc already holds the exp2 arguments (weights pre-scaled).
        const float ei = EXP2F(acc[i][0]);        // e^{-gi}
        const float ef = EXP2F(acc[i][1]);        // e^{-gf}
        const float eg = EXP2F(acc[i][2]);        // e^{-2gg}
        const float eo = EXP2F(acc[i][3]);        // e^{-go}
        const float pf = 1.f + ef, pi_ = 1.f + ei, pg = 1.f + eg, mg = 1.f - eg;
        const float pp = pi_ * pg;
        float c1 = c1st[i];
        c1 = fmaf(c1, pp, pf * mg) * fastrcp(pf * pp);
        c1st[i] = c1;
        cl[i] = c1;
        // h1 = sig(go)*tanh(c1); clamp matches exp-domain 80 (115.4/log2e)
        const float ec = EXP2F(fminf(115.4f, c1 * -L2E2));
        const float h1 = (1.f - ec) * fastrcp((1.f + eo) * (1.f + ec));
        // RNE hi + RNE lo via HW bf16 converts
        const __hip_bfloat16 bh(h1);
        const float df = h1 - (float)bh;
        const __hip_bfloat16 bl(df);
        hp[i] = (unsigned)*(const unsigned short*)&bh |
                ((unsigned)*(const unsigned short*)&bl << 16);
    }
    const int base = iloc * PADK;
    if (NTc == 4) {
        *(u32x4*)&Hw[base + (SL * 4 + kq) * 8] =
            (u32x4){hp[0], hp[1], hp[2], hp[3]};
        const unsigned s01 = (hp[0] & 0xffffu) | (hp[1] << 16);
        const unsigned s23 = (hp[2] & 0xffffu) | (hp[3] << 16);
        *(u32x2*)&Hw[base + 104 + (SL * 4 + kq) * 4] = (u32x2){s01, s23};
        *(f32x4*)&C1w[iloc * 52 + SL * 16 + kq * 4] =
            (f32x4){cl[0], cl[1], cl[2], cl[3]};
    } else {
        const bool ok = (48 + kq) < H1;           // kq==3 -> scratch
        *(unsigned*)&Hw[base + (ok ? 96 + 2 * kq : 160)] = hp[0];
        Hw[base + (ok ? 152 + kq : 164)] = (short)hp[0];
        C1w[iloc * 52 + 48 + kq] = cl[0];         // p=51 is scratch (Wz[51]=0)
    }
}

// Fill one 64-step x-chunk into Xbuf (wave 1, all 64 lanes), packed hi|lo.
__device__ __forceinline__ void xchunk_fill(const float* __restrict__ input, int r0, int c,
                                            int lane, unsigned (*Xb)[64 * 16]) {
    const int m = lane & 15, q = lane >> 4;
    const int tt = c * 64 + q * 16;
    f32x4 v[4];
    if (tt < SEQT) {
        const float* src = input + (size_t)(r0 + m) * SEQT + tt;
#pragma unroll
        for (int p = 0; p < 4; ++p) v[p] = *(const f32x4*)(src + 4 * p);
    } else {
#pragma unroll
        for (int p = 0; p < 4; ++p) v[p] = (f32x4){0.f, 0.f, 0.f, 0.f};
    }
#pragma unroll
    for (int p = 0; p < 4; ++p)
#pragma unroll
        for (int j = 0; j < 4; ++j)
            Xb[c & 1][(q * 16 + p * 4 + j) * 16 + m] = pack_hilo(v[p][j]);
}

__global__ void __launch_bounds__(256)
__attribute__((amdgpu_waves_per_eu(1)))
lstm_fused_kernel(const float* __restrict__ input,
                  const float* __restrict__ W_ih1,
                  const float* __restrict__ W_hh1,
                  const float* __restrict__ b_ih1,
                  const float* __restrict__ b_hh1,
                  const float* __restrict__ W_ih3,
                  const float* __restrict__ W_hh3,
                  const float* __restrict__ b_ih3,
                  const float* __restrict__ b_hh3,
                  float* __restrict__ out) {
    const int t = threadIdx.x;
    const int w = t >> 6;          // wave 0..3
    const int lane = t & 63;
    const int iloc = lane & 15, kq = lane >> 4;
    const int r0 = blockIdx.x * MROW;

    __shared__ short Hst[2][MROW * PADK];      // staged h/x/bias rows, parity dbuf
    __shared__ float C1buf[2][MROW * 52];      // raw f32 c1 (permuted u), parity dbuf
    __shared__ float Obuf[2][MROW * OSTR];     // c3 chunks
    __shared__ unsigned Xbuf[2][64 * 16];      // packed x hi/lo, 64-step chunks

    // tile assignment: w0 {0-3} SL0, w2 {4-7} SL1 + x, w3 {8-11} SL2,
    // w1 {12} + LSTM3
    const int NT = (w == 1) ? 1 : 4;
    const int tb = (w == 0) ? 0 : (w == 1) ? 12 : (w == 2) ? 4 : 8;

    // ---- gate-row weight fragments (A-operand, permuted map, exp2-scaled) ----
    s16x8 Wfr[4][5];
#pragma unroll
    for (int i = 0; i < 4; ++i) {
        if (i < NT) {
            const int np = (tb + i) * 16 + iloc;
            const int u_r = np >> 2, g_r = np & 3;
            const int n = g_r * H1 + u_r;
            const bool vr = (u_r < H1);
            const float sc = (g_r == 2) ? -L2E2 : -L2E;
#pragma unroll
            for (int kt = 0; kt < 5; ++kt) {
                s16x8 bf;
#pragma unroll
                for (int j = 0; j < 8; ++j)
                    bf[j] = f2bf(aval(W_hh1, W_ih1, b_ih1, b_hh1, n, sc, vr,
                                      kt * 32 + kq * 8 + j));
                Wfr[i][kt] = bf;
            }
        }
    }

    // ---- wave 1: LSTM3 constants (log2-scaled). lane (m,g3) ----
    const int g3 = lane >> 4;
    const float scg3 = (g3 == 2) ? L2E2 : -L2E;   // kg * log2e
    float Wz[52];
    if (w == 1) {
#pragma unroll
        for (int p = 0; p < 52; ++p) {
            const int u = (p < 48) ? (16 * (p >> 4) + 4 * (p & 3) + ((p >> 2) & 3))
                                   : p;
            Wz[p] = (u < H1) ? scg3 * W_ih3[g3 * H1 + u] : 0.f;
        }
    }
    const float whh3g = scg3 * W_hh3[g3];
    const float b3g = scg3 * (b_ih3[g3] + b_hh3[g3]);
    const float ag = (g3 == 2) ? -2.f : 1.f;
    const float bg = (g3 == 2) ? 1.f : 0.f;

    // ---- LDS init ----
    for (int idx = t; idx < 2 * MROW * PADK; idx += 256)
        ((short*)Hst)[idx] = 0;
    for (int idx = t; idx < 2 * MROW * 52; idx += 256)
        ((float*)C1buf)[idx] = 0.f;
    __syncthreads();   // zeros before targeted writes
    if (t < MROW) {
        const int m = t;
#pragma unroll
        for (int p = 0; p < 2; ++p) {
            Hst[p][m * PADK + 156] = (short)0x3F80;   // 1.0 (bias cols)
            Hst[p][m * PADK + 157] = (short)0x3F80;
        }
        const float x0 = input[(size_t)(r0 + m) * SEQT];
        const unsigned xp = pack_hilo(x0);
        Hst[1][m * PADK + 102] = (short)xp;   // step 0 reads parity 1
        Hst[1][m * PADK + 103] = (short)(xp >> 16);
        Hst[1][m * PADK + 155] = (short)xp;
    }
    if (w == 1) {                 // prefill x chunks 0 and 1
        xchunk_fill(input, r0, 0, lane, Xbuf);
        xchunk_fill(input, r0, 1, lane, Xbuf);
    }
    float c1st[4] = {0.f, 0.f, 0.f, 0.f};
    float h3 = 0.f, c3 = 0.f;   // LSTM3 state (wave 1, lanes 0..15 valid)
    float h3b = 0.f;            // h3 broadcast across wave-1 lanes (per m)

    // LSTM3 body for step s, reading c1v (already loaded). RBc = C1 parity.
    auto lstm3_step = [&](const f32x4 (&c1v)[13], int s) {
        float d0a = 0.f, d1a = 0.f, d2a = 0.f, d3a = 0.f;
        float d0b = 0.f, d1b = 0.f, d2b = 0.f, d3b = 0.f;
#pragma unroll
        for (int j = 0; j < 13; ++j) {
            if ((j & 1) == 0) {
                d0a = fmaf(Wz[4 * j + 0], c1v[j][0], d0a);
                d1a = fmaf(Wz[4 * j + 1], c1v[j][1], d1a);
                d2a = fmaf(Wz[4 * j + 2], c1v[j][2], d2a);
                d3a = fmaf(Wz[4 * j + 3], c1v[j][3], d3a);
            } else {
                d0b = fmaf(Wz[4 * j + 0], c1v[j][0], d0b);
                d1b = fmaf(Wz[4 * j + 1], c1v[j][1], d1b);
                d2b = fmaf(Wz[4 * j + 2], c1v[j][2], d2b);
                d3b = fmaf(Wz[4 * j + 3], c1v[j][3], d3b);
            }
        }
        const float z = ((d0a + d0b) + (d1a + d1b)) +
                        ((d2a + d2b) + (d3a + d3b));
        const float pre = z + fmaf(whh3g, h3b, b3g);
        const float act = bg + ag * fastrcp(EXP2F(pre) + 1.f);
        const float act1 = __shfl_xor(act, 16, 64);
        const float act2 = __shfl_xor(act, 32, 64);
        const float act3 = __shfl_xor(act, 48, 64);
        if (lane < MROW) {   // lanes<16: act=i, act1=f, act2=g, act3=o
            c3 = act1 * c3 + act * act2;
            h3 = act3 * tanhfast(c3);
            Obuf[(s >> 6) & 1][lane * OSTR + (s & 63)] = c3;
        }
        h3b = __shfl(h3, lane & 15, 64);
    };

#pragma unroll 1
    for (int ts2 = 0; ts2 < SEQT; ts2 += 2) {
        // ============ EVEN step ts=ts2: rb=1, wb=0; carries x-fill ============
        {
            const int ts = ts2;
            __syncthreads();
            s16x8 hf[5];
#pragma unroll
            for (int kt = 0; kt < 5; ++kt)
                hf[kt] = *(const s16x8*)&Hst[1][iloc * PADK + kt * 32 + kq * 8];
            f32x4 c1v[13];
            if (w == 1 && ts > 0) {
                const float* cr = &C1buf[1][(lane & 15) * 52];
#pragma unroll
                for (int j = 0; j < 13; ++j)
                    c1v[j] = *(const f32x4*)(cr + 4 * j);
            }
            // x chunk fill: issue loads early (store at step bottom)
            const bool fill = (w == 1) && ((ts & 63) == 0) && (ts >= 64) &&
                              ((ts >> 6) < 31);
            const int fc = (ts >> 6) + 1;
            f32x4 xv[4];
            if (fill) {
                const int fm = lane & 15, fq = lane >> 4;
                const int tt = fc * 64 + fq * 16;
                if (tt < SEQT) {
                    const float* src = input + (size_t)(r0 + fm) * SEQT + tt;
#pragma unroll
                    for (int p = 0; p < 4; ++p) xv[p] = *(const f32x4*)(src + 4 * p);
                } else {
#pragma unroll
                    for (int p = 0; p < 4; ++p) xv[p] = (f32x4){0.f, 0.f, 0.f, 0.f};
                }
            }
            short* Hw = &Hst[0][0];
            float* C1w = &C1buf[0][0];
            if (w == 0) {
                run_tiles<0, 4>(Wfr, hf, c1st, Hw, C1w, iloc, kq);
            } else if (w == 2) {
                const int t1 = ts + 1;
                const int m2 = lane & 15;
                const unsigned pv = Xbuf[(t1 >> 6) & 1][(t1 & 63) * 16 + m2];
                *(unsigned*)&Hw[m2 * PADK + 102] = pv;
                Hw[m2 * PADK + 155] = (short)pv;
                run_tiles<1, 4>(Wfr, hf, c1st, Hw, C1w, iloc, kq);
            } else if (w == 3) {
                run_tiles<2, 4>(Wfr, hf, c1st, Hw, C1w, iloc, kq);
            } else {
                run_tiles<3, 1>(Wfr, hf, c1st, Hw, C1w, iloc, kq);
            }
            if (w == 1 && ts > 0)
                lstm3_step(c1v, ts - 1);
            if (fill) {
                const int fm = lane & 15, fq = lane >> 4;
#pragma unroll
                for (int p = 0; p < 4; ++p)
#pragma unroll
                    for (int j = 0; j < 4; ++j)
                        Xbuf[fc & 1][(fq * 16 + p * 4 + j) * 16 + fm] =
                            pack_hilo(xv[p][j]);
            }
        }
        // ============ ODD step ts=ts2+1: rb=0, wb=1; carries dump ============
        {
            const int ts = ts2 + 1;
            __syncthreads();
            s16x8 hf[5];
#pragma unroll
            for (int kt = 0; kt < 5; ++kt)
                hf[kt] = *(const s16x8*)&Hst[0][iloc * PADK + kt * 32 + kq * 8];
            f32x4 c1v[13];
            if (w == 1) {
                const float* cr = &C1buf[0][(lane & 15) * 52];
#pragma unroll
                for (int j = 0; j < 13; ++j)
                    c1v[j] = *(const f32x4*)(cr + 4 * j);
            }
            // coalesced dump of finished 64-chunk (odd-only trigger)
            if (ts >= 65 && (ts & 63) == 1) {
                const int c = (ts >> 6) - 1;
#pragma unroll
                for (int rep = 0; rep < 4; ++rep) {
                    const int row = w + 4 * rep;
                    out[(size_t)(r0 + row) * SEQT + c * 64 + lane] =
                        Obuf[c & 1][row * OSTR + lane];
                }
            }
            short* Hw = &Hst[1][0];
            float* C1w = &C1buf[1][0];
            if (w == 0) {
                run_tiles<0, 4>(Wfr, hf, c1st, Hw, C1w, iloc, kq);
            } else if (w == 2) {
                const int t1 = ts + 1;
                if (t1 < SEQT) {
                    const int m2 = lane & 15;
                    const unsigned pv = Xbuf[(t1 >> 6) & 1][(t1 & 63) * 16 + m2];
                    *(unsigned*)&Hw[m2 * PADK + 102] = pv;
                    Hw[m2 * PADK + 155] = (short)pv;
                }
                run_tiles<1, 4>(Wfr, hf, c1st, Hw, C1w, iloc, kq);
            } else if (w == 3) {
                run_tiles<2, 4>(Wfr, hf, c1st, Hw, C1w, iloc, kq);
            } else {
                run_tiles<3, 1>(Wfr, hf, c1st, Hw, C1w, iloc, kq);
            }
            if (w == 1)
                lstm3_step(c1v, ts - 1);
        }
    }

    // ---- epilogue interval (ts = SEQT): LSTM3 for step 1999 ----
    __syncthreads();
    if (w == 1) {
        f32x4 c1v[13];
        const float* cr = &C1buf[1][(lane & 15) * 52];   // written at ts=1999 (wb=1)
#pragma unroll
        for (int j = 0; j < 13; ++j)
            c1v[j] = *(const f32x4*)(cr + 4 * j);
        lstm3_step(c1v, SEQT - 1);
    }

    __syncthreads();
    // tail: steps 1984..1999 (chunk 31, parity 1)
    {
        const int row = t >> 4, pos = t & 15;
        out[(size_t)(r0 + row) * SEQT + 1984 + pos] = Obuf[1][row * OSTR + pos];
    }
}

extern "C" void kernel_launch(void* const* d_in, const int* in_sizes, int n_in,
                              void* d_out, int out_size, void* d_ws, size_t ws_size,
                              hipStream_t stream) {
    const float* input = (const float*)d_in[0];
    const float* W_ih1 = (const float*)d_in[1];
    const float* W_hh1 = (const float*)d_in[2];
    const float* b_ih1 = (const float*)d_in[3];
    const float* b_hh1 = (const float*)d_in[4];
    const float* W_ih3 = (const float*)d_in[5];
    const float* W_hh3 = (const float*)d_in[6];
    const float* b_ih3 = (const float*)d_in[7];
    const float* b_hh3 = (const float*)d_in[8];
    float* out = (float*)d_out;

    lstm_fused_kernel<<<NBLK, 256, 0, stream>>>(
        input, W_ih1, W_hh1, b_ih1, b_hh1, W_ih3, W_hh3, b_ih3, b_hh3, out);
}

// Round 13
// 1298.009 us; speedup vs baseline: 2.2951x; 1.1274x over previous
//
#include <hip/hip_runtime.h>
#include <hip/hip_bf16.h>

#define SEQT 2000
#define NB   2048
#define H1   51
#define MROW 16
#define NBLK (NB / MROW)   // 128 blocks, 256 threads (4 waves)
#define PADK 168           // shorts per staged row (336 B = 21*16, 16B-aligned)
#define OSTR 65            // Obuf row stride (floats) — odd, conflict-free

// log2(e) and 2*log2(e)
#define L2E  1.4426950408889634f
#define L2E2 2.8853900817779268f

typedef float f32x4 __attribute__((ext_vector_type(4)));
typedef short s16x8 __attribute__((ext_vector_type(8)));
typedef unsigned u32x4 __attribute__((ext_vector_type(4)));
typedef unsigned u32x2 __attribute__((ext_vector_type(2)));

#if __has_builtin(__builtin_amdgcn_exp2f)
#define EXP2F(x) __builtin_amdgcn_exp2f(x)
#else
#define EXP2F(x) __expf((x) * 0.6931471805599453f)   // exp(x*ln2) == 2^x
#endif

template <bool B> struct BoolC { static constexpr bool value = B; };

__device__ __forceinline__ short f2bf(float f) { __hip_bfloat16 b(f); return *(short*)&b; }
__device__ __forceinline__ float bf2f(short s) { __hip_bfloat16 b; *(short*)&b = s; return (float)b; }
__device__ __forceinline__ float rbf(float f) { return bf2f(f2bf(f)); }
__device__ __forceinline__ float fastrcp(float x) { return __builtin_amdgcn_rcpf(x); }
__device__ __forceinline__ float tanhfast(float x) {
    return 1.f - 2.f * fastrcp(EXP2F(x * L2E2) + 1.f);
}

__device__ __forceinline__ unsigned rne_bf16(float v) {
    unsigned b = __float_as_uint(v);
    return (b + 0x7fffu + ((b >> 16) & 1u)) >> 16;
}
// packed (hi | lo<<16), both RNE — off the hot path (x staging)
__device__ __forceinline__ unsigned pack_hilo(float v) {
    const unsigned hh = rne_bf16(v);
    const float hi = __uint_as_float(hh << 16);
    const unsigned hl = rne_bf16(v - hi);
    return hh | (hl << 16);
}

__device__ __forceinline__ f32x4 mfma16(s16x8 a, s16x8 b, f32x4 c) {
    return __builtin_amdgcn_mfma_f32_16x16x32_bf16(a, b, c, 0, 0, 0);
}

// ---------------------------------------------------------------------------
// Staged-vector column map, K=160 (5 k-tiles of 32). Columns permuted so every
// per-step write is coalesced; x and bias live inside the matmul.
//   0..95   : (h_hi,h_lo) pairs vs Whh_hi. col=(sl*4+kq)*8+2i+{0,1}, tile=sl*4+i
//   96..101 : w1 pairs (u=48+kq, kq=0..2) vs Whh_hi
//   102,103 : x_hi, x_lo vs Wih_hi
//   104..151: h_hi singles vs Whh_lo. col=104+(sl*4+kq)*4+i
//   152..154: w1 singles (u=48+kq) vs Whh_lo
//   155     : x_hi vs Wih_lo
//   156,157 : 1.0 vs bias_hi / bias_lo    158,159: 0    160..167: scratch
// EXP2 FOLD: A-rows pre-scaled by -log2e (i/f/o) / -2log2e (g) so
// e_gate = exp2(acc) directly off the MFMA accumulator.
// MFMA: single-accumulator chains (r7/r8 A/B: dual-acc join costs ~150 cy).
// LSTM3 (H3=1): w1 reads C1 rows, 52-FMA dot (8 acc), 64-lane activation
// spread, shfl_xor gate gather, c3/h3 on lanes 0..15.
// R11: unroll-2 compile-time parity (the -23% lever: constant LDS indices ->
// no per-access address math + free scheduling).
// R12: boundary/clean pair specialization — fill/dump code + guards exist only
// in the 3% of pairs that need them; x-staging moved w2 -> w1 (w0/w2/w3 are
// now identical pure-4-tile waves); both steps' x read once at pair top.
// Numerics bit-identical to r11 (1463 us).
// ---------------------------------------------------------------------------

__device__ __forceinline__ float aval(const float* __restrict__ W_hh1,
                                      const float* __restrict__ W_ih1,
                                      const float* __restrict__ b_ih1,
                                      const float* __restrict__ b_hh1,
                                      int n, float sc, bool vr, int k) {
    if (!vr) return 0.f;
    if (k < 96) {
        const int gp = k >> 3, j = k & 7;
        const int u = 4 * ((gp >> 2) * 4 + (j >> 1)) + (gp & 3);
        return rbf(sc * W_hh1[n * H1 + u]);
    } else if (k < 102) {
        const int u = 48 + ((k - 96) >> 1);
        return rbf(sc * W_hh1[n * H1 + u]);
    } else if (k < 104) {
        return rbf(sc * W_ih1[n]);               // x_hi / x_lo vs Wih_hi
    } else if (k < 152) {
        const int d = k - 104;
        const int gp = d >> 2;
        const int u = 4 * ((gp >> 2) * 4 + (d & 3)) + (gp & 3);
        const float wv = sc * W_hh1[n * H1 + u];
        return wv - rbf(wv);
    } else if (k < 155) {
        const int u = 48 + (k - 152);
        const float wv = sc * W_hh1[n * H1 + u];
        return wv - rbf(wv);
    } else if (k == 155) {
        const float wv = sc * W_ih1[n];
        return wv - rbf(wv);
    } else if (k == 156) {
        return rbf(sc * (b_ih1[n] + b_hh1[n]));
    } else if (k == 157) {
        const float bv = sc * (b_ih1[n] + b_hh1[n]);
        return bv - rbf(bv);
    }
    return 0.f;
}

template <int SL, int NTc>
__device__ __forceinline__ void run_tiles(const s16x8 (&Wfr)[4][5], const s16x8 (&hf)[5],
                                          float (&c1st)[4], short* __restrict__ Hw,
                                          float* __restrict__ C1w,
                                          const int iloc, const int kq) {
    f32x4 acc[4];
#pragma unroll
    for (int i = 0; i < NTc; ++i) {
        // single accumulator chain (independent tiles pipeline the latency)
        f32x4 a = (f32x4){0.f, 0.f, 0.f, 0.f};
        a = mfma16(Wfr[i][0], hf[0], a);
        a = mfma16(Wfr[i][1], hf[1], a);
        a = mfma16(Wfr[i][2], hf[2], a);
        a = mfma16(Wfr[i][3], hf[3], a);
        a = mfma16(Wfr[i][4], hf[4], a);
        acc[i] = a;
    }
    unsigned hp[4];
    float cl[4];
#pragma unroll
    for (int i = 0; i < NTc; ++i) {
        // acc already holds the exp2 arguments (weights pre-scaled).
        const float ei = EXP2F(acc[i][0]);        // e^{-gi}
        const float ef = EXP2F(acc[i][1]);        // e^{-gf}
        const float eg = EXP2F(acc[i][2]);        // e^{-2gg}
        const float eo = EXP2F(acc[i][3]);        // e^{-go}
        const float pf = 1.f + ef, pi_ = 1.f + ei, pg = 1.f + eg, mg = 1.f - eg;
        const float pp = pi_ * pg;
        float c1 = c1st[i];
        c1 = fmaf(c1, pp, pf * mg) * fastrcp(pf * pp);
        c1st[i] = c1;
        cl[i] = c1;
        // h1 = sig(go)*tanh(c1); clamp matches exp-domain 80 (115.4/log2e)
        const float ec = EXP2F(fminf(115.4f, c1 * -L2E2));
        const float h1 = (1.f - ec) * fastrcp((1.f + eo) * (1.f + ec));
        // RNE hi + RNE lo via HW bf16 converts
        const __hip_bfloat16 bh(h1);
        const float df = h1 - (float)bh;
        const __hip_bfloat16 bl(df);
        hp[i] = (unsigned)*(const unsigned short*)&bh |
                ((unsigned)*(const unsigned short*)&bl << 16);
    }
    const int base = iloc * PADK;
    if (NTc == 4) {
        *(u32x4*)&Hw[base + (SL * 4 + kq) * 8] =
            (u32x4){hp[0], hp[1], hp[2], hp[3]};
        const unsigned s01 = (hp[0] & 0xffffu) | (hp[1] << 16);
        const unsigned s23 = (hp[2] & 0xffffu) | (hp[3] << 16);
        *(u32x2*)&Hw[base + 104 + (SL * 4 + kq) * 4] = (u32x2){s01, s23};
        *(f32x4*)&C1w[iloc * 52 + SL * 16 + kq * 4] =
            (f32x4){cl[0], cl[1], cl[2], cl[3]};
    } else {
        const bool ok = (48 + kq) < H1;           // kq==3 -> scratch
        *(unsigned*)&Hw[base + (ok ? 96 + 2 * kq : 160)] = hp[0];
        Hw[base + (ok ? 152 + kq : 164)] = (short)hp[0];
        C1w[iloc * 52 + 48 + kq] = cl[0];         // p=51 is scratch (Wz[51]=0)
    }
}

// Fill one 64-step x-chunk into Xbuf (wave 1, all 64 lanes), packed hi|lo.
__device__ __forceinline__ void xchunk_fill(const float* __restrict__ input, int r0, int c,
                                            int lane, unsigned (*Xb)[64 * 16]) {
    const int m = lane & 15, q = lane >> 4;
    const int tt = c * 64 + q * 16;
    f32x4 v[4];
    if (tt < SEQT) {
        const float* src = input + (size_t)(r0 + m) * SEQT + tt;
#pragma unroll
        for (int p = 0; p < 4; ++p) v[p] = *(const f32x4*)(src + 4 * p);
    } else {
#pragma unroll
        for (int p = 0; p < 4; ++p) v[p] = (f32x4){0.f, 0.f, 0.f, 0.f};
    }
#pragma unroll
    for (int p = 0; p < 4; ++p)
#pragma unroll
        for (int j = 0; j < 4; ++j)
            Xb[c & 1][(q * 16 + p * 4 + j) * 16 + m] = pack_hilo(v[p][j]);
}

__global__ void __launch_bounds__(256)
__attribute__((amdgpu_waves_per_eu(1)))
lstm_fused_kernel(const float* __restrict__ input,
                  const float* __restrict__ W_ih1,
                  const float* __restrict__ W_hh1,
                  const float* __restrict__ b_ih1,
                  const float* __restrict__ b_hh1,
                  const float* __restrict__ W_ih3,
                  const float* __restrict__ W_hh3,
                  const float* __restrict__ b_ih3,
                  const float* __restrict__ b_hh3,
                  float* __restrict__ out) {
    const int t = threadIdx.x;
    const int w = t >> 6;          // wave 0..3
    const int lane = t & 63;
    const int iloc = lane & 15, kq = lane >> 4;
    const int r0 = blockIdx.x * MROW;

    __shared__ short Hst[2][MROW * PADK];      // staged h/x/bias rows, parity dbuf
    __shared__ float C1buf[2][MROW * 52];      // raw f32 c1 (permuted u), parity dbuf
    __shared__ float Obuf[2][MROW * OSTR];     // c3 chunks
    __shared__ unsigned Xbuf[2][64 * 16];      // packed x hi/lo, 64-step chunks

    // tile assignment: w0 {0-3} SL0, w2 {4-7} SL1, w3 {8-11} SL2 (pure tiles),
    // w1 {12} + LSTM3 + x-staging + x-fill
    const int NT = (w == 1) ? 1 : 4;
    const int tb = (w == 0) ? 0 : (w == 1) ? 12 : (w == 2) ? 4 : 8;

    // ---- gate-row weight fragments (A-operand, permuted map, exp2-scaled) ----
    s16x8 Wfr[4][5];
#pragma unroll
    for (int i = 0; i < 4; ++i) {
        if (i < NT) {
            const int np = (tb + i) * 16 + iloc;
            const int u_r = np >> 2, g_r = np & 3;
            const int n = g_r * H1 + u_r;
            const bool vr = (u_r < H1);
            const float sc = (g_r == 2) ? -L2E2 : -L2E;
#pragma unroll
            for (int kt = 0; kt < 5; ++kt) {
                s16x8 bf;
#pragma unroll
                for (int j = 0; j < 8; ++j)
                    bf[j] = f2bf(aval(W_hh1, W_ih1, b_ih1, b_hh1, n, sc, vr,
                                      kt * 32 + kq * 8 + j));
                Wfr[i][kt] = bf;
            }
        }
    }

    // ---- wave 1: LSTM3 constants (log2-scaled). lane (m,g3) ----
    const int g3 = lane >> 4;
    const float scg3 = (g3 == 2) ? L2E2 : -L2E;   // kg * log2e
    float Wz[52];
    if (w == 1) {
#pragma unroll
        for (int p = 0; p < 52; ++p) {
            const int u = (p < 48) ? (16 * (p >> 4) + 4 * (p & 3) + ((p >> 2) & 3))
                                   : p;
            Wz[p] = (u < H1) ? scg3 * W_ih3[g3 * H1 + u] : 0.f;
        }
    }
    const float whh3g = scg3 * W_hh3[g3];
    const float b3g = scg3 * (b_ih3[g3] + b_hh3[g3]);
    const float ag = (g3 == 2) ? -2.f : 1.f;
    const float bg = (g3 == 2) ? 1.f : 0.f;

    // ---- LDS init ----
    for (int idx = t; idx < 2 * MROW * PADK; idx += 256)
        ((short*)Hst)[idx] = 0;
    for (int idx = t; idx < 2 * MROW * 52; idx += 256)
        ((float*)C1buf)[idx] = 0.f;
    __syncthreads();   // zeros before targeted writes
    if (t < MROW) {
        const int m = t;
#pragma unroll
        for (int p = 0; p < 2; ++p) {
            Hst[p][m * PADK + 156] = (short)0x3F80;   // 1.0 (bias cols)
            Hst[p][m * PADK + 157] = (short)0x3F80;
        }
        const float x0 = input[(size_t)(r0 + m) * SEQT];
        const unsigned xp = pack_hilo(x0);
        Hst[1][m * PADK + 102] = (short)xp;   // step 0 reads parity 1
        Hst[1][m * PADK + 103] = (short)(xp >> 16);
        Hst[1][m * PADK + 155] = (short)xp;
    }
    if (w == 1) {                 // prefill x chunks 0 and 1
        xchunk_fill(input, r0, 0, lane, Xbuf);
        xchunk_fill(input, r0, 1, lane, Xbuf);
    }
    float c1st[4] = {0.f, 0.f, 0.f, 0.f};
    float h3 = 0.f, c3 = 0.f;   // LSTM3 state (wave 1, lanes 0..15 valid)
    float h3b = 0.f;            // h3 broadcast across wave-1 lanes (per m)

    // LSTM3 body for step s, reading c1v (already loaded).
    auto lstm3_step = [&](const f32x4 (&c1v)[13], int s) {
        float d0a = 0.f, d1a = 0.f, d2a = 0.f, d3a = 0.f;
        float d0b = 0.f, d1b = 0.f, d2b = 0.f, d3b = 0.f;
#pragma unroll
        for (int j = 0; j < 13; ++j) {
            if ((j & 1) == 0) {
                d0a = fmaf(Wz[4 * j + 0], c1v[j][0], d0a);
                d1a = fmaf(Wz[4 * j + 1], c1v[j][1], d1a);
                d2a = fmaf(Wz[4 * j + 2], c1v[j][2], d2a);
                d3a = fmaf(Wz[4 * j + 3], c1v[j][3], d3a);
            } else {
                d0b = fmaf(Wz[4 * j + 0], c1v[j][0], d0b);
                d1b = fmaf(Wz[4 * j + 1], c1v[j][1], d1b);
                d2b = fmaf(Wz[4 * j + 2], c1v[j][2], d2b);
                d3b = fmaf(Wz[4 * j + 3], c1v[j][3], d3b);
            }
        }
        const float z = ((d0a + d0b) + (d1a + d1b)) +
                        ((d2a + d2b) + (d3a + d3b));
        const float pre = z + fmaf(whh3g, h3b, b3g);
        const float act = bg + ag * fastrcp(EXP2F(pre) + 1.f);
        const float act1 = __shfl_xor(act, 16, 64);
        const float act2 = __shfl_xor(act, 32, 64);
        const float act3 = __shfl_xor(act, 48, 64);
        if (lane < MROW) {   // lanes<16: act=i, act1=f, act2=g, act3=o
            c3 = act1 * c3 + act * act2;
            h3 = act3 * tanhfast(c3);
            Obuf[(s >> 6) & 1][lane * OSTR + (s & 63)] = c3;
        }
        h3b = __shfl(h3, lane & 15, 64);
    };

    // One unrolled pair (even step tsE reads Hst[1]/writes Hst[0]; odd step
    // tsE+1 reads Hst[0]/writes Hst[1]). FILL/DUMP compile-time — clean pairs
    // (97%) carry neither the code nor the guards.
    auto do_pair = [&](const int tsE, auto fillc, auto dumpc) {
        constexpr bool FILL = decltype(fillc)::value;
        constexpr bool DUMP = decltype(dumpc)::value;
        unsigned pv2 = 0;                        // x(tsE+2), staged in odd step
        // ================= EVEN step =================
        __syncthreads();
        {
            s16x8 hf[5];
#pragma unroll
            for (int kt = 0; kt < 5; ++kt)
                hf[kt] = *(const s16x8*)&Hst[1][iloc * PADK + kt * 32 + kq * 8];
            f32x4 c1v[13];
            unsigned pv1 = 0;
            if (w == 1) {
                const float* cr = &C1buf[1][(lane & 15) * 52];
#pragma unroll
                for (int j = 0; j < 13; ++j)
                    c1v[j] = *(const f32x4*)(cr + 4 * j);
                const int t1 = tsE + 1;
                pv1 = Xbuf[(t1 >> 6) & 1][(t1 & 63) * 16 + (lane & 15)];
                if (tsE + 2 < SEQT) {
                    const int t2 = tsE + 2;
                    pv2 = Xbuf[(t2 >> 6) & 1][(t2 & 63) * 16 + (lane & 15)];
                }
            }
            f32x4 xv[4];
            if (FILL && w == 1) {                // load next x chunk (fc = c+1)
                const int fc = (tsE >> 6) + 1;
                const int fm = lane & 15, fq = lane >> 4;
                const int tt = fc * 64 + fq * 16;
                if (tt < SEQT) {
                    const float* src = input + (size_t)(r0 + fm) * SEQT + tt;
#pragma unroll
                    for (int p = 0; p < 4; ++p) xv[p] = *(const f32x4*)(src + 4 * p);
                } else {
#pragma unroll
                    for (int p = 0; p < 4; ++p) xv[p] = (f32x4){0.f, 0.f, 0.f, 0.f};
                }
            }
            short* Hw = &Hst[0][0];
            float* C1w = &C1buf[0][0];
            if (w == 0) {
                run_tiles<0, 4>(Wfr, hf, c1st, Hw, C1w, iloc, kq);
            } else if (w == 2) {
                run_tiles<1, 4>(Wfr, hf, c1st, Hw, C1w, iloc, kq);
            } else if (w == 3) {
                run_tiles<2, 4>(Wfr, hf, c1st, Hw, C1w, iloc, kq);
            } else {
                // stage x(tsE+1) into Hst[0] (cols 102/103/155)
                const int m2 = lane & 15;
                *(unsigned*)&Hw[m2 * PADK + 102] = pv1;
                Hw[m2 * PADK + 155] = (short)pv1;
                run_tiles<3, 1>(Wfr, hf, c1st, Hw, C1w, iloc, kq);
                if (tsE > 0)
                    lstm3_step(c1v, tsE - 1);
            }
            if (FILL && w == 1) {                // pack + store (loads landed)
                const int fc = (tsE >> 6) + 1;
                const int fm = lane & 15, fq = lane >> 4;
#pragma unroll
                for (int p = 0; p < 4; ++p)
#pragma unroll
                    for (int j = 0; j < 4; ++j)
                        Xbuf[fc & 1][(fq * 16 + p * 4 + j) * 16 + fm] =
                            pack_hilo(xv[p][j]);
            }
        }
        // ================= ODD step =================
        __syncthreads();
        {
            const int tsO = tsE + 1;
            s16x8 hf[5];
#pragma unroll
            for (int kt = 0; kt < 5; ++kt)
                hf[kt] = *(const s16x8*)&Hst[0][iloc * PADK + kt * 32 + kq * 8];
            f32x4 c1v[13];
            if (w == 1) {
                const float* cr = &C1buf[0][(lane & 15) * 52];
#pragma unroll
                for (int j = 0; j < 13; ++j)
                    c1v[j] = *(const f32x4*)(cr + 4 * j);
            }
            if (DUMP) {                          // dump finished 64-chunk
                const int c = (tsO >> 6) - 1;
#pragma unroll
                for (int rep = 0; rep < 4; ++rep) {
                    const int row = w + 4 * rep;
                    out[(size_t)(r0 + row) * SEQT + c * 64 + lane] =
                        Obuf[c & 1][row * OSTR + lane];
                }
            }
            short* Hw = &Hst[1][0];
            float* C1w = &C1buf[1][0];
            if (w == 0) {
                run_tiles<0, 4>(Wfr, hf, c1st, Hw, C1w, iloc, kq);
            } else if (w == 2) {
                run_tiles<1, 4>(Wfr, hf, c1st, Hw, C1w, iloc, kq);
            } else if (w == 3) {
                run_tiles<2, 4>(Wfr, hf, c1st, Hw, C1w, iloc, kq);
            } else {
                // stage x(tsE+2) into Hst[1] (value read at pair top)
                if (tsE + 2 < SEQT) {
                    const int m2 = lane & 15;
                    *(unsigned*)&Hw[m2 * PADK + 102] = pv2;
                    Hw[m2 * PADK + 155] = (short)pv2;
                }
                run_tiles<3, 1>(Wfr, hf, c1st, Hw, C1w, iloc, kq);
                lstm3_step(c1v, tsO - 1);
            }
        }
    };

    // chunks 0..30 full (64 steps = 32 pairs), chunk 31 partial (16 = 8 pairs).
    // Boundary pair of chunk c carries: fill (c in 1..30), dump (c >= 1).
#pragma unroll 1
    for (int c = 0; c < 32; ++c) {
        const int base = c << 6;
        int p0 = 0;
        if (c >= 1 && c < 31) {
            do_pair(base, BoolC<true>{}, BoolC<true>{});
            p0 = 1;
        } else if (c == 31) {
            do_pair(base, BoolC<false>{}, BoolC<true>{});
            p0 = 1;
        }
        const int npairs = (c == 31) ? 8 : 32;
#pragma unroll 1
        for (int p = p0; p < npairs; ++p)
            do_pair(base + (p << 1), BoolC<false>{}, BoolC<false>{});
    }

    // ---- epilogue: LSTM3 for step 1999 (c1 written at ts=1999, parity 1) ----
    __syncthreads();
    if (w == 1) {
        f32x4 c1v[13];
        const float* cr = &C1buf[1][(lane & 15) * 52];
#pragma unroll
        for (int j = 0; j < 13; ++j)
            c1v[j] = *(const f32x4*)(cr + 4 * j);
        lstm3_step(c1v, SEQT - 1);
    }

    __syncthreads();
    // tail: steps 1984..1999 (chunk 31, parity 1)
    {
        const int row = t >> 4, pos = t & 15;
        out[(size_t)(r0 + row) * SEQT + 1984 + pos] = Obuf[1][row * OSTR + pos];
    }
}

extern "C" void kernel_launch(void* const* d_in, const int* in_sizes, int n_in,
                              void* d_out, int out_size, void* d_ws, size_t ws_size,
                              hipStream_t stream) {
    const float* input = (const float*)d_in[0];
    const float* W_ih1 = (const float*)d_in[1];
    const float* W_hh1 = (const float*)d_in[2];
    const float* b_ih1 = (const float*)d_in[3];
    const float* b_hh1 = (const float*)d_in[4];
    const float* W_ih3 = (const float*)d_in[5];
    const float* W_hh3 = (const float*)d_in[6];
    const float* b_ih3 = (const float*)d_in[7];
    const float* b_hh3 = (const float*)d_in[8];
    float* out = (float*)d_out;

    lstm_fused_kernel<<<NBLK, 256, 0, stream>>>(
        input, W_ih1, W_hh1, b_ih1, b_hh1, W_ih3, W_hh3, b_ih3, b_hh3, out);
}

// Round 14
// 1167.057 us; speedup vs baseline: 2.5526x; 1.1122x over previous
//
#include <hip/hip_runtime.h>
#include <hip/hip_bf16.h>

#define SEQT 2000
#define NB   2048
#define H1   51
#define MROW 16
#define NBLK (NB / MROW)   // 128 blocks, 256 threads (4 waves)
#define PADK 168           // shorts per staged row (336 B = 21*16, 16B-aligned)
#define OSTR 65            // Obuf row stride (floats) — odd, conflict-free

// log2(e) and 2*log2(e)
#define L2E  1.4426950408889634f
#define L2E2 2.8853900817779268f

typedef float f32x4 __attribute__((ext_vector_type(4)));
typedef short s16x8 __attribute__((ext_vector_type(8)));
typedef unsigned u32x4 __attribute__((ext_vector_type(4)));
typedef unsigned u32x2 __attribute__((ext_vector_type(2)));

#if __has_builtin(__builtin_amdgcn_exp2f)
#define EXP2F(x) __builtin_amdgcn_exp2f(x)
#else
#define EXP2F(x) __expf((x) * 0.6931471805599453f)   // exp(x*ln2) == 2^x
#endif

template <bool B> struct BoolC { static constexpr bool value = B; };
template <int V>  struct IntC  { static constexpr int  value = V; };

__device__ __forceinline__ short f2bf(float f) { __hip_bfloat16 b(f); return *(short*)&b; }
__device__ __forceinline__ float bf2f(short s) { __hip_bfloat16 b; *(short*)&b = s; return (float)b; }
__device__ __forceinline__ float rbf(float f) { return bf2f(f2bf(f)); }
__device__ __forceinline__ float fastrcp(float x) { return __builtin_amdgcn_rcpf(x); }
__device__ __forceinline__ float tanhfast(float x) {
    return 1.f - 2.f * fastrcp(EXP2F(x * L2E2) + 1.f);
}

__device__ __forceinline__ unsigned rne_bf16(float v) {
    unsigned b = __float_as_uint(v);
    return (b + 0x7fffu + ((b >> 16) & 1u)) >> 16;
}
// packed (hi | lo<<16), both RNE — off the hot path (x staging)
__device__ __forceinline__ unsigned pack_hilo(float v) {
    const unsigned hh = rne_bf16(v);
    const float hi = __uint_as_float(hh << 16);
    const unsigned hl = rne_bf16(v - hi);
    return hh | (hl << 16);
}

__device__ __forceinline__ f32x4 mfma16(s16x8 a, s16x8 b, f32x4 c) {
    return __builtin_amdgcn_mfma_f32_16x16x32_bf16(a, b, c, 0, 0, 0);
}

// ---------------------------------------------------------------------------
// Staged-vector column map, K=160 (5 k-tiles of 32). Columns permuted so every
// per-step write is coalesced; x and bias live inside the matmul.
//   0..95   : (h_hi,h_lo) pairs vs Whh_hi. col=(sl*4+kq)*8+2i+{0,1}, tile=sl*4+i
//   96..101 : w1 pairs (u=48+kq, kq=0..2) vs Whh_hi
//   102,103 : x_hi, x_lo vs Wih_hi
//   104..151: h_hi singles vs Whh_lo. col=104+(sl*4+kq)*4+i
//   152..154: w1 singles (u=48+kq) vs Whh_lo
//   155     : x_hi vs Wih_lo
//   156,157 : 1.0 vs bias_hi / bias_lo    158,159: 0    160..167: scratch
// EXP2 FOLD: A-rows pre-scaled by -log2e (i/f/o) / -2log2e (g).
// MFMA: single-accumulator chains (r7/r8: dual-acc join costs ~150 cy).
// R11: unroll-2 compile-time parity. R12: boundary/clean pair specialization.
// R13: (a) WAVE-SPECIALIZED time loops (template W — no per-step wave
// branches, constant slot/dump addressing, cross-step scheduling);
// (b) LSTM3 z via PER-WAVE PARTIALS: tile waves fold sc3(g)*W3[g][u]*c1[u]
// over their 4 tiles and write ONE b128 (replacing the C1 b128) to Zbuf;
// w1 reads 16 b32 + 15-add tree instead of 13 b128 + 52-FMA dot — cuts the
// DS pipe (~60cy) and w1 issue (~130cy). (c) FIRST/LAST pair variants.
// ---------------------------------------------------------------------------

__device__ __forceinline__ float aval(const float* __restrict__ W_hh1,
                                      const float* __restrict__ W_ih1,
                                      const float* __restrict__ b_ih1,
                                      const float* __restrict__ b_hh1,
                                      int n, float sc, bool vr, int k) {
    if (!vr) return 0.f;
    if (k < 96) {
        const int gp = k >> 3, j = k & 7;
        const int u = 4 * ((gp >> 2) * 4 + (j >> 1)) + (gp & 3);
        return rbf(sc * W_hh1[n * H1 + u]);
    } else if (k < 102) {
        const int u = 48 + ((k - 96) >> 1);
        return rbf(sc * W_hh1[n * H1 + u]);
    } else if (k < 104) {
        return rbf(sc * W_ih1[n]);               // x_hi / x_lo vs Wih_hi
    } else if (k < 152) {
        const int d = k - 104;
        const int gp = d >> 2;
        const int u = 4 * ((gp >> 2) * 4 + (d & 3)) + (gp & 3);
        const float wv = sc * W_hh1[n * H1 + u];
        return wv - rbf(wv);
    } else if (k < 155) {
        const int u = 48 + (k - 152);
        const float wv = sc * W_hh1[n * H1 + u];
        return wv - rbf(wv);
    } else if (k == 155) {
        const float wv = sc * W_ih1[n];
        return wv - rbf(wv);
    } else if (k == 156) {
        return rbf(sc * (b_ih1[n] + b_hh1[n]));
    } else if (k == 157) {
        const float bv = sc * (b_ih1[n] + b_hh1[n]);
        return bv - rbf(bv);
    }
    return 0.f;
}

template <int SL, int NTc>
__device__ __forceinline__ void run_tiles(const s16x8 (&Wfr)[4][5], const s16x8 (&hf)[5],
                                          float (&c1st)[4], const float (&W3c)[4][4],
                                          short* __restrict__ Hw,
                                          float* __restrict__ Zw,
                                          const int iloc, const int kq) {
    f32x4 acc[4];
#pragma unroll
    for (int i = 0; i < NTc; ++i) {
        // single accumulator chain (independent tiles pipeline the latency)
        f32x4 a = (f32x4){0.f, 0.f, 0.f, 0.f};
        a = mfma16(Wfr[i][0], hf[0], a);
        a = mfma16(Wfr[i][1], hf[1], a);
        a = mfma16(Wfr[i][2], hf[2], a);
        a = mfma16(Wfr[i][3], hf[3], a);
        a = mfma16(Wfr[i][4], hf[4], a);
        acc[i] = a;
    }
    unsigned hp[4];
    float zp0 = 0.f, zp1 = 0.f, zp2 = 0.f, zp3 = 0.f;
#pragma unroll
    for (int i = 0; i < NTc; ++i) {
        // acc already holds the exp2 arguments (weights pre-scaled).
        const float ei = EXP2F(acc[i][0]);        // e^{-gi}
        const float ef = EXP2F(acc[i][1]);        // e^{-gf}
        const float eg = EXP2F(acc[i][2]);        // e^{-2gg}
        const float eo = EXP2F(acc[i][3]);        // e^{-go}
        const float pf = 1.f + ef, pi_ = 1.f + ei, pg = 1.f + eg, mg = 1.f - eg;
        const float pp = pi_ * pg;
        float c1 = c1st[i];
        c1 = fmaf(c1, pp, pf * mg) * fastrcp(pf * pp);
        c1st[i] = c1;
        // LSTM3 z-partials for this lane's units (W3c pre-scaled per gate)
        zp0 = fmaf(W3c[i][0], c1, zp0);
        zp1 = fmaf(W3c[i][1], c1, zp1);
        zp2 = fmaf(W3c[i][2], c1, zp2);
        zp3 = fmaf(W3c[i][3], c1, zp3);
        // h1 = sig(go)*tanh(c1); clamp matches exp-domain 80 (115.4/log2e)
        const float ec = EXP2F(fminf(115.4f, c1 * -L2E2));
        const float h1 = (1.f - ec) * fastrcp((1.f + eo) * (1.f + ec));
        // RNE hi + RNE lo via HW bf16 converts
        const __hip_bfloat16 bh(h1);
        const float df = h1 - (float)bh;
        const __hip_bfloat16 bl(df);
        hp[i] = (unsigned)*(const unsigned short*)&bh |
                ((unsigned)*(const unsigned short*)&bl << 16);
    }
    const int base = iloc * PADK;
    if (NTc == 4) {
        *(u32x4*)&Hw[base + (SL * 4 + kq) * 8] =
            (u32x4){hp[0], hp[1], hp[2], hp[3]};
        const unsigned s01 = (hp[0] & 0xffffu) | (hp[1] << 16);
        const unsigned s23 = (hp[2] & 0xffffu) | (hp[3] << 16);
        *(u32x2*)&Hw[base + 104 + (SL * 4 + kq) * 4] = (u32x2){s01, s23};
    } else {
        const bool ok = (48 + kq) < H1;           // kq==3 -> scratch
        *(unsigned*)&Hw[base + (ok ? 96 + 2 * kq : 160)] = hp[0];
        Hw[base + (ok ? 152 + kq : 164)] = (short)hp[0];
    }
    *(f32x4*)Zw = (f32x4){zp0, zp1, zp2, zp3};
}

// Fill one 64-step x-chunk into Xbuf (wave 1, all 64 lanes), packed hi|lo.
__device__ __forceinline__ void xchunk_fill(const float* __restrict__ input, int r0, int c,
                                            int lane, unsigned (*Xb)[64 * 16]) {
    const int m = lane & 15, q = lane >> 4;
    const int tt = c * 64 + q * 16;
    f32x4 v[4];
    if (tt < SEQT) {
        const float* src = input + (size_t)(r0 + m) * SEQT + tt;
#pragma unroll
        for (int p = 0; p < 4; ++p) v[p] = *(const f32x4*)(src + 4 * p);
    } else {
#pragma unroll
        for (int p = 0; p < 4; ++p) v[p] = (f32x4){0.f, 0.f, 0.f, 0.f};
    }
#pragma unroll
    for (int p = 0; p < 4; ++p)
#pragma unroll
        for (int j = 0; j < 4; ++j)
            Xb[c & 1][(q * 16 + p * 4 + j) * 16 + m] = pack_hilo(v[p][j]);
}

__global__ void __launch_bounds__(256)
__attribute__((amdgpu_waves_per_eu(1)))
lstm_fused_kernel(const float* __restrict__ input,
                  const float* __restrict__ W_ih1,
                  const float* __restrict__ W_hh1,
                  const float* __restrict__ b_ih1,
                  const float* __restrict__ b_hh1,
                  const float* __restrict__ W_ih3,
                  const float* __restrict__ W_hh3,
                  const float* __restrict__ b_ih3,
                  const float* __restrict__ b_hh3,
                  float* __restrict__ out) {
    const int t = threadIdx.x;
    const int w = t >> 6;          // wave 0..3
    const int lane = t & 63;
    const int iloc = lane & 15, kq = lane >> 4;
    const int r0 = blockIdx.x * MROW;

    __shared__ short Hst[2][MROW * PADK];      // staged h/x/bias rows, parity dbuf
    __shared__ float Obuf[2][MROW * OSTR];     // c3 chunks
    __shared__ unsigned Xbuf[2][64 * 16];      // packed x hi/lo, 64-step chunks
    __shared__ float Zbuf[2][16][16][4];       // z-partials [par][slot][m][g]

    // tile assignment: w0 SL0 {0-3}, w2 SL1 {4-7}, w3 SL2 {8-11} (pure tiles),
    // w1 SL3 {12} + LSTM3 + x-staging + x-fill
    const int NT = (w == 1) ? 1 : 4;
    const int tb = (w == 0) ? 0 : (w == 1) ? 12 : (w == 2) ? 4 : 8;

    // ---- gate-row weight fragments (A-operand, permuted map, exp2-scaled) ----
    s16x8 Wfr[4][5];
#pragma unroll
    for (int i = 0; i < 4; ++i) {
        if (i < NT) {
            const int np = (tb + i) * 16 + iloc;
            const int u_r = np >> 2, g_r = np & 3;
            const int n = g_r * H1 + u_r;
            const bool vr = (u_r < H1);
            const float sc = (g_r == 2) ? -L2E2 : -L2E;
#pragma unroll
            for (int kt = 0; kt < 5; ++kt) {
                s16x8 bf;
#pragma unroll
                for (int j = 0; j < 8; ++j)
                    bf[j] = f2bf(aval(W_hh1, W_ih1, b_ih1, b_hh1, n, sc, vr,
                                      kt * 32 + kq * 8 + j));
                Wfr[i][kt] = bf;
            }
        }
    }

    // ---- LSTM3 input-weight constants per lane unit (pre-scaled per gate) ----
    float W3c[4][4];
#pragma unroll
    for (int i = 0; i < 4; ++i) {
        const int u = (tb + i) * 4 + kq;
        const bool ok = (i < NT) && (u < H1);
#pragma unroll
        for (int g = 0; g < 4; ++g)
            W3c[i][g] = ok ? ((g == 2) ? L2E2 : -L2E) * W_ih3[g * H1 + u] : 0.f;
    }

    // ---- wave 1: LSTM3 activation constants. lane (m,g3) ----
    const int g3 = lane >> 4;
    const float scg3 = (g3 == 2) ? L2E2 : -L2E;   // kg * log2e
    const float whh3g = scg3 * W_hh3[g3];
    const float b3g = scg3 * (b_ih3[g3] + b_hh3[g3]);
    const float ag = (g3 == 2) ? -2.f : 1.f;
    const float bg = (g3 == 2) ? 1.f : 0.f;

    // ---- LDS init ----
    for (int idx = t; idx < 2 * MROW * PADK; idx += 256)
        ((short*)Hst)[idx] = 0;
    __syncthreads();   // zeros before targeted writes
    if (t < MROW) {
        const int m = t;
#pragma unroll
        for (int p = 0; p < 2; ++p) {
            Hst[p][m * PADK + 156] = (short)0x3F80;   // 1.0 (bias cols)
            Hst[p][m * PADK + 157] = (short)0x3F80;
        }
        const float x0 = input[(size_t)(r0 + m) * SEQT];
        const unsigned xp = pack_hilo(x0);
        Hst[1][m * PADK + 102] = (short)xp;   // step 0 reads parity 1
        Hst[1][m * PADK + 103] = (short)(xp >> 16);
        Hst[1][m * PADK + 155] = (short)xp;
    }
    if (w == 1) {                 // prefill x chunks 0 and 1
        xchunk_fill(input, r0, 0, lane, Xbuf);
        xchunk_fill(input, r0, 1, lane, Xbuf);
    }
    float c1st[4] = {0.f, 0.f, 0.f, 0.f};
    float h3 = 0.f, c3 = 0.f;   // LSTM3 state (wave 1, lanes 0..15 valid)
    float h3b = 0.f;            // h3 broadcast across wave-1 lanes (per m)

    // LSTM3 body for step s, from the 16 z-partials (one per slot).
    auto lstm3_step = [&](const float (&zv)[16], int s) {
        const float z =
            (((zv[0] + zv[1]) + (zv[2] + zv[3])) +
             ((zv[4] + zv[5]) + (zv[6] + zv[7]))) +
            (((zv[8] + zv[9]) + (zv[10] + zv[11])) +
             ((zv[12] + zv[13]) + (zv[14] + zv[15])));
        const float pre = z + fmaf(whh3g, h3b, b3g);
        const float act = bg + ag * fastrcp(EXP2F(pre) + 1.f);
        const float act1 = __shfl_xor(act, 16, 64);
        const float act2 = __shfl_xor(act, 32, 64);
        const float act3 = __shfl_xor(act, 48, 64);
        if (lane < MROW) {   // lanes<16: act=i, act1=f, act2=g, act3=o
            c3 = act1 * c3 + act * act2;
            h3 = act3 * tanhfast(c3);
            Obuf[(s >> 6) & 1][lane * OSTR + (s & 63)] = c3;
        }
        h3b = __shfl(h3, lane & 15, 64);
    };

    // One unrolled pair, wave-specialized (compile-time W). Even step reads
    // Hst[1]/Zbuf[1], writes Hst[0]/Zbuf[0]; odd step the reverse.
    auto do_pair = [&](auto wc, auto fc, auto dc, auto fic, auto lac,
                       const int tsE) {
        constexpr int W = decltype(wc)::value;
        constexpr bool FILL = decltype(fc)::value;
        constexpr bool DUMP = decltype(dc)::value;
        constexpr bool FIRST = decltype(fic)::value;
        constexpr bool LAST = decltype(lac)::value;
        constexpr int SL = (W == 0) ? 0 : (W == 1) ? 3 : (W == 2) ? 1 : 2;
        unsigned pv2 = 0;                        // x(tsE+2), staged in odd step
        // ================= EVEN step =================
        __syncthreads();
        {
            s16x8 hf[5];
#pragma unroll
            for (int kt = 0; kt < 5; ++kt)
                hf[kt] = *(const s16x8*)&Hst[1][iloc * PADK + kt * 32 + kq * 8];
            float zv[16];
            unsigned pv1 = 0;
            if constexpr (W == 1) {
                if constexpr (!FIRST) {
#pragma unroll
                    for (int q = 0; q < 16; ++q)
                        zv[q] = Zbuf[1][q][lane & 15][g3];
                }
                const int t1 = tsE + 1;
                pv1 = Xbuf[(t1 >> 6) & 1][(t1 & 63) * 16 + (lane & 15)];
                if constexpr (!LAST) {
                    const int t2 = tsE + 2;
                    pv2 = Xbuf[(t2 >> 6) & 1][(t2 & 63) * 16 + (lane & 15)];
                }
            }
            f32x4 xv[4];
            if constexpr (FILL && W == 1) {      // load next x chunk
                const int fc2 = (tsE >> 6) + 1;
                const int fm = lane & 15, fq = lane >> 4;
                const int tt = fc2 * 64 + fq * 16;
                if (tt < SEQT) {
                    const float* src = input + (size_t)(r0 + fm) * SEQT + tt;
#pragma unroll
                    for (int p = 0; p < 4; ++p) xv[p] = *(const f32x4*)(src + 4 * p);
                } else {
#pragma unroll
                    for (int p = 0; p < 4; ++p) xv[p] = (f32x4){0.f, 0.f, 0.f, 0.f};
                }
            }
            short* Hw = &Hst[0][0];
            float* Zw = &Zbuf[0][SL * 4 + kq][iloc][0];
            if constexpr (W == 1) {
                // stage x(tsE+1) into Hst[0] (cols 102/103/155)
                const int m2 = lane & 15;
                *(unsigned*)&Hw[m2 * PADK + 102] = pv1;
                Hw[m2 * PADK + 155] = (short)pv1;
                run_tiles<3, 1>(Wfr, hf, c1st, W3c, Hw, Zw, iloc, kq);
                if constexpr (!FIRST)
                    lstm3_step(zv, tsE - 1);
            } else {
                run_tiles<SL, 4>(Wfr, hf, c1st, W3c, Hw, Zw, iloc, kq);
            }
            if constexpr (FILL && W == 1) {      // pack + store (loads landed)
                const int fc2 = (tsE >> 6) + 1;
                const int fm = lane & 15, fq = lane >> 4;
#pragma unroll
                for (int p = 0; p < 4; ++p)
#pragma unroll
                    for (int j = 0; j < 4; ++j)
                        Xbuf[fc2 & 1][(fq * 16 + p * 4 + j) * 16 + fm] =
                            pack_hilo(xv[p][j]);
            }
        }
        // ================= ODD step =================
        __syncthreads();
        {
            const int tsO = tsE + 1;
            s16x8 hf[5];
#pragma unroll
            for (int kt = 0; kt < 5; ++kt)
                hf[kt] = *(const s16x8*)&Hst[0][iloc * PADK + kt * 32 + kq * 8];
            float zv[16];
            if constexpr (W == 1) {
#pragma unroll
                for (int q = 0; q < 16; ++q)
                    zv[q] = Zbuf[0][q][lane & 15][g3];
            }
            if constexpr (DUMP) {                // dump finished 64-chunk
                const int c = (tsO >> 6) - 1;
#pragma unroll
                for (int rep = 0; rep < 4; ++rep) {
                    const int row = W + 4 * rep;
                    out[(size_t)(r0 + row) * SEQT + c * 64 + lane] =
                        Obuf[c & 1][row * OSTR + lane];
                }
            }
            short* Hw = &Hst[1][0];
            float* Zw = &Zbuf[1][SL * 4 + kq][iloc][0];
            if constexpr (W == 1) {
                if constexpr (!LAST) {           // stage x(tsE+2) into Hst[1]
                    const int m2 = lane & 15;
                    *(unsigned*)&Hw[m2 * PADK + 102] = pv2;
                    Hw[m2 * PADK + 155] = (short)pv2;
                }
                run_tiles<3, 1>(Wfr, hf, c1st, W3c, Hw, Zw, iloc, kq);
                lstm3_step(zv, tsO - 1);
            } else {
                run_tiles<SL, 4>(Wfr, hf, c1st, W3c, Hw, Zw, iloc, kq);
            }
        }
    };

    // Wave-specialized chunk iteration. chunks 0..30 full (32 pairs), chunk 31
    // partial (8 pairs). Boundary pair of chunk c: fill (1<=c<=30), dump (c>=1).
    auto run_chunks = [&](auto wc) {
        constexpr BoolC<false> F{};
        constexpr BoolC<true>  T{};
        // chunk 0: pair 0 is FIRST, rest clean
        do_pair(wc, F, F, T, F, 0);
#pragma unroll 1
        for (int p = 1; p < 32; ++p)
            do_pair(wc, F, F, F, F, p << 1);
#pragma unroll 1
        for (int c = 1; c < 31; ++c) {
            do_pair(wc, T, T, F, F, c << 6);
#pragma unroll 1
            for (int p = 1; p < 32; ++p)
                do_pair(wc, F, F, F, F, (c << 6) + (p << 1));
        }
        // chunk 31: dump-only boundary, 6 clean, LAST
        do_pair(wc, F, T, F, F, 31 << 6);
#pragma unroll 1
        for (int p = 1; p < 7; ++p)
            do_pair(wc, F, F, F, F, (31 << 6) + (p << 1));
        do_pair(wc, F, F, F, T, (31 << 6) + 14);
    };

    if (w == 0)      run_chunks(IntC<0>{});
    else if (w == 1) run_chunks(IntC<1>{});
    else if (w == 2) run_chunks(IntC<2>{});
    else             run_chunks(IntC<3>{});

    // ---- epilogue: LSTM3 for step 1999 (z written at ts=1999, parity 1) ----
    __syncthreads();
    if (w == 1) {
        float zv[16];
#pragma unroll
        for (int q = 0; q < 16; ++q)
            zv[q] = Zbuf[1][q][lane & 15][g3];
        lstm3_step(zv, SEQT - 1);
    }

    __syncthreads();
    // tail: steps 1984..1999 (chunk 31, parity 1)
    {
        const int row = t >> 4, pos = t & 15;
        out[(size_t)(r0 + row) * SEQT + 1984 + pos] = Obuf[1][row * OSTR + pos];
    }
}

extern "C" void kernel_launch(void* const* d_in, const int* in_sizes, int n_in,
                              void* d_out, int out_size, void* d_ws, size_t ws_size,
                              hipStream_t stream) {
    const float* input = (const float*)d_in[0];
    const float* W_ih1 = (const float*)d_in[1];
    const float* W_hh1 = (const float*)d_in[2];
    const float* b_ih1 = (const float*)d_in[3];
    const float* b_hh1 = (const float*)d_in[4];
    const float* W_ih3 = (const float*)d_in[5];
    const float* W_hh3 = (const float*)d_in[6];
    const float* b_ih3 = (const float*)d_in[7];
    const float* b_hh3 = (const float*)d_in[8];
    float* out = (float*)d_out;

    lstm_fused_kernel<<<NBLK, 256, 0, stream>>>(
        input, W_ih1, W_hh1, b_ih1, b_hh1, W_ih3, W_hh3, b_ih3, b_hh3, out);
}